// Round 6
// baseline (184.908 us; speedup 1.0000x reference)
//
#include <hip/hip_runtime.h>
#include <hip/hip_bf16.h>
#include <math.h>

// Problem constants (ModernBERT attention)
#define BATCH 4
#define SEQ   2048
#define DMODEL 768
#define NHEADS 12
#define HDIM  64
#define WIN   64          // window each side
#define QKV_LD 2304       // 3*DMODEL

typedef __attribute__((ext_vector_type(8))) short bf16x8;  // 8 bf16 = 4 VGPRs
typedef __attribute__((ext_vector_type(4))) float f32x4;

typedef __attribute__((address_space(1))) const unsigned int guint;
typedef __attribute__((address_space(3))) unsigned int luint;

__device__ inline void gl_lds16(const __hip_bfloat16* g, __hip_bfloat16* l) {
    __builtin_amdgcn_global_load_lds((guint*)g, (luint*)l, 16, 0, 0);
}

__device__ inline void to_out(float* p, float v) { *p = v; }
__device__ inline void to_out(__hip_bfloat16* p, float v) { *p = __float2bfloat16(v); }

// BK=32 chunk swizzle: 4 chunks/row; bijective per row, and on the read side
// lanes fr, fr+4, fr+8, fr+12 (same bank parity) get 4 DISTINCT slots
// -> <=2-way LDS bank aliasing (free, m136).
__device__ inline int swz4(int r) { return (r + (r >> 2)) & 3; }

// ---------------------------------------------------------------------------
// fused setup: cast hidden/Wqkv/Wo to bf16 + build rope cos/sin table.
// ---------------------------------------------------------------------------
#define N4_HID  (BATCH * SEQ * DMODEL / 4)     // 1,572,864
#define N4_WQKV (QKV_LD * DMODEL / 4)          //   442,368
#define N4_WO   (DMODEL * DMODEL / 4)          //   147,456
#define N_ROPE  (SEQ * 32)                     //    65,536
#define SETUP_TOTAL (N4_HID + N4_WQKV + N4_WO + N_ROPE)

__device__ inline void cast4(const float* in, __hip_bfloat16* out, int i) {
    float4 v = ((const float4*)in)[i];
    union { ushort4 u; __hip_bfloat16 h[4]; } o;
    o.h[0] = __float2bfloat16(v.x); o.h[1] = __float2bfloat16(v.y);
    o.h[2] = __float2bfloat16(v.z); o.h[3] = __float2bfloat16(v.w);
    ((ushort4*)out)[i] = o.u;
}

__global__ __launch_bounds__(256) void setup_kernel(const float* __restrict__ hidden,
                                                    const float* __restrict__ Wqkv,
                                                    const float* __restrict__ Wo,
                                                    __hip_bfloat16* __restrict__ hid_bf,
                                                    __hip_bfloat16* __restrict__ wqkv_bf,
                                                    __hip_bfloat16* __restrict__ wo_bf,
                                                    float2* __restrict__ tab) {
    int id = blockIdx.x * 256 + threadIdx.x;
    if (id < N4_HID) {
        cast4(hidden, hid_bf, id);
    } else if (id < N4_HID + N4_WQKV) {
        cast4(Wqkv, wqkv_bf, id - N4_HID);
    } else if (id < N4_HID + N4_WQKV + N4_WO) {
        cast4(Wo, wo_bf, id - N4_HID - N4_WQKV);
    } else if (id < SETUP_TOTAL) {
        int idx = id - (N4_HID + N4_WQKV + N4_WO);
        int t = idx >> 5, j = idx & 31;
        const float L2T_OVER_32 = 13.287712379549449f / 32.0f;  // log2(10000)/32
        float inv = exp2f(-(float)j * L2T_OVER_32);
        float s, c;
        sincosf((float)t * inv, &s, &c);
        tab[idx] = make_float2(c, s);
    }
}

// ---------------------------------------------------------------------------
// Counted-vmcnt ring bf16 MFMA NT GEMM, BK=32 for occupancy.
// BM=128, BN=64*NWN, BK=32, K=768 (24 K-tiles). 256 threads = 4 waves.
// NWN=2 (QKV): 2x2 waves, per-wave 64x64; LDS 2x(8+8)=32 KB -> 4-5 blk/CU
//   (grid 1152 = 4.5/CU). Previous BK=64/64KB ring pinned OccupancyPercent
//   at ~15% (2 blk/CU) across R1-R5 with MfmaUtil ~21-26%, VALUBusy ~15%:
//   latency-bound, TLP-starved. BK=32 doubles resident blocks; per-wave
//   MFMA:ds_read stays 2.0 (8 b128 reads -> 16 MFMA per tile).
// NWN=1 (Wo): 4x1 waves, per-wave 32x64; LDS 24 KB; grid 768 = 3/CU.
// Schedule = R3's counted ring (best measured): vmcnt(own-stage loads) ->
// raw s_barrier -> compute slot t&1 -> s_barrier -> stage(t+2).
// Loads/stage/thread: A 2 + B NWN -> vmcnt(4) / vmcnt(3); tail vmcnt(0).
// ---------------------------------------------------------------------------
template <typename OutT, int NWN, bool ROPE>
__global__ __launch_bounds__(256) void gemm_k32(const __hip_bfloat16* __restrict__ A,
                                                const __hip_bfloat16* __restrict__ B,
                                                OutT* __restrict__ C,
                                                int lda, int ldb, int ldc,
                                                const float2* __restrict__ rope_tab) {
    constexpr int BN    = 64 * NWN;       // 128 or 64
    constexpr int NWM   = 4 / NWN;        // 2 or 4
    constexpr int WM    = 128 / NWM;      // 64 or 32
    constexpr int MI    = WM / 16;        // 4 or 2
    constexpr int ASLOT = 128 * 32;       // elements per A ring slot (8 KB)
    constexpr int BSLOT = BN * 32;        // elements per B ring slot
    constexpr int NT    = 768 / 32;       // 24 K-tiles

    __shared__ __align__(16) __hip_bfloat16 As[2 * ASLOT];
    __shared__ __align__(16) __hip_bfloat16 Bs[2 * BSLOT];

    const int tid  = threadIdx.x;
    const int lane = tid & 63;
    const int wave = tid >> 6;     // 0..3
    const int wm   = wave / NWN;
    const int wn   = wave % NWN;
    const int fr   = lane & 15;
    const int quad = lane >> 4;

    // XCD-aware swizzle (gridM = 64 m-tiles, 8 per XCD)
    const int bid = blockIdx.x;
    const int x   = bid & 7;
    const int j   = bid >> 3;
    const int m0  = (x * 8 + (j & 7)) * 128;
    const int n0  = (j >> 3) * BN;

    f32x4 acc[MI][4];
#pragma unroll
    for (int i = 0; i < MI; i++)
#pragma unroll
        for (int jj = 0; jj < 4; jj++) acc[i][jj] = (f32x4){0.f, 0.f, 0.f, 0.f};

    // stage one 128x32 A-tile (512 chunks -> 2 insts/thread) + BNx32 B-tile
    // (BN*4 chunks -> NWN insts/thread) into ring slot t&1.
    auto stage = [&](int t) {
        const int s  = t & 1;
        const int k0 = t * 32;
#pragma unroll
        for (int c = 0; c < 2; ++c) {
            int tc  = c * 256 + tid;          // 0..511
            int row = tc >> 2, ch = tc & 3;
            int gcol = (ch ^ swz4(row)) * 8;
            gl_lds16(A + (size_t)(m0 + row) * lda + k0 + gcol, As + s * ASLOT + tc * 8);
        }
#pragma unroll
        for (int c = 0; c < NWN; ++c) {
            int tc  = c * 256 + tid;          // 0..(BN*4-1)
            int row = tc >> 2, ch = tc & 3;
            int gcol = (ch ^ swz4(row)) * 8;
            gl_lds16(B + (size_t)(n0 + row) * ldb + k0 + gcol, Bs + s * BSLOT + tc * 8);
        }
    };

    // prologue: 2 tiles in flight
    stage(0); stage(1);

#pragma unroll
    for (int t = 0; t < NT; ++t) {
        // retire tile t's own loads; tile t+1's stay in flight (counted wait).
        if (t < NT - 1) {
            if constexpr (NWN == 2) asm volatile("s_waitcnt vmcnt(4)" ::: "memory");
            else                    asm volatile("s_waitcnt vmcnt(3)" ::: "memory");
        } else {
            asm volatile("s_waitcnt vmcnt(0)" ::: "memory");
        }
        __builtin_amdgcn_s_barrier();          // raw: no implicit drain
        __builtin_amdgcn_sched_barrier(0);     // pin: no reads hoisted above

        const __hip_bfloat16* as = As + (t & 1) * ASLOT;
        const __hip_bfloat16* bs = Bs + (t & 1) * BSLOT;
        bf16x8 af[MI], bfv[4];
#pragma unroll
        for (int mi = 0; mi < MI; ++mi) {
            int row = wm * WM + mi * 16 + fr;
            int pos = quad ^ swz4(row);
            af[mi] = *(const bf16x8*)(as + row * 32 + pos * 8);
        }
#pragma unroll
        for (int ni = 0; ni < 4; ++ni) {
            int row = wn * 64 + ni * 16 + fr;
            int pos = quad ^ swz4(row);
            bfv[ni] = *(const bf16x8*)(bs + row * 32 + pos * 8);
        }
        __builtin_amdgcn_s_setprio(1);
#pragma unroll
        for (int mi = 0; mi < MI; ++mi)
#pragma unroll
            for (int ni = 0; ni < 4; ++ni)
                acc[mi][ni] = __builtin_amdgcn_mfma_f32_16x16x32_bf16(af[mi], bfv[ni], acc[mi][ni], 0, 0, 0);
        __builtin_amdgcn_s_setprio(0);

        if (t < NT - 2) {
            __builtin_amdgcn_s_barrier();      // all waves done reading slot t&1
            __builtin_amdgcn_sched_barrier(0);
            stage(t + 2);                      // refill the vacated slot
        }
    }

    // fused RoPE: 64-col group b0 covers exactly one head; pairs (ni, ni+2)
    const int b0 = n0 + wn * 64;
    if (ROPE && b0 < 2 * DMODEL) {
#pragma unroll
        for (int mi = 0; mi < MI; mi++) {
#pragma unroll
            for (int r = 0; r < 4; r++) {
                int t = (m0 + wm * WM + mi * 16 + quad * 4 + r) & (SEQ - 1);
#pragma unroll
                for (int ni = 0; ni < 2; ni++) {
                    float2 cs = rope_tab[t * 32 + ni * 16 + fr];
                    float x0 = acc[mi][ni][r], x1 = acc[mi][ni + 2][r];
                    acc[mi][ni][r]     = x0 * cs.x - x1 * cs.y;
                    acc[mi][ni + 2][r] = x0 * cs.y + x1 * cs.x;
                }
            }
        }
    }

    // direct scalar-store epilogue (no barriers)
#pragma unroll
    for (int mi = 0; mi < MI; mi++)
#pragma unroll
        for (int ni = 0; ni < 4; ni++) {
            f32x4 v = acc[mi][ni];
            int gc = b0 + ni * 16 + fr;
            size_t rbase = (size_t)(m0 + wm * WM + mi * 16 + quad * 4);
#pragma unroll
            for (int r = 0; r < 4; r++)
                to_out(&C[(rbase + r) * ldc + gc], v[r]);
        }
}

// ---------------------------------------------------------------------------
// Sliding-window attention, one block per (b, head, 64-query tile).
// QK^T and PV via MFMA; in-register softmax via quad-group shuffles.
// Q fragments loaded directly from global. K staged stride 64 + XOR swizzle.
// LDS 48 KB -> 3 blocks/CU.
// ---------------------------------------------------------------------------
#define PLD  192

__global__ __launch_bounds__(256) void attn_kernel(const __hip_bfloat16* __restrict__ qkv,
                                                   const int* __restrict__ mask,
                                                   __hip_bfloat16* __restrict__ attn) {
    __shared__ __align__(16) char smem[49152];
    __hip_bfloat16* Ks = (__hip_bfloat16*)smem;            // [192][64] swizzled
    __hip_bfloat16* Pb = (__hip_bfloat16*)smem;            // [64][192] swizzled (aliases Ks)
    __hip_bfloat16* Vt = (__hip_bfloat16*)(smem + 24576);  // [64][192] swizzled

    const int tid  = threadIdx.x;
    const int lane = tid & 63;
    const int wave = tid >> 6;
    const int fr   = lane & 15;
    const int quad = lane >> 4;

    // XCD-aware swizzle: 1536 blocks = 8 XCDs x 192
    const int bid  = blockIdx.x;
    const int x    = bid & 7;
    const int j    = bid >> 3;                 // 0..191
    const int b    = x >> 1;
    const int q0   = ((x & 1) * 16 + (j & 15)) * 64;
    const int head = j >> 4;                   // 0..11

    const int klo = max(0, q0 - WIN);
    const int khi = min(SEQ, q0 + 64 + WIN);
    const int nk  = khi - klo;     // 128 or 192
    const int nt  = nk >> 4;       // 8 or 12
    const int nkc = nk >> 5;       // 4 or 6

    const size_t rowbase = (size_t)(b * SEQ) * QKV_LD + head * HDIM;

    // ---- stage K [nk][64] XOR-swizzled: up to 1536 uint4 tasks
    for (int task = tid; task < nk * 8; task += 256) {
        int row = task >> 3, g = task & 7;
        uint4 v = *(const uint4*)(qkv + rowbase + (size_t)(klo + row) * QKV_LD + DMODEL + g * 8);
        *(uint4*)(Ks + row * 64 + (g ^ (row & 7)) * 8) = v;
    }
    // ---- stage V transposed [64][nk], XOR-swizzled chunks of 8
    {
        int h = lane;
        const __hip_bfloat16* vb = qkv + rowbase + 2 * DMODEL + h;
        int ng = nk >> 3;
        for (int g = wave; g < ng; g += 4) {
            unsigned int u0, u1, u2, u3;
            {
                unsigned short a0 = *(const unsigned short*)(vb + (size_t)(klo + g * 8 + 0) * QKV_LD);
                unsigned short a1 = *(const unsigned short*)(vb + (size_t)(klo + g * 8 + 1) * QKV_LD);
                unsigned short a2 = *(const unsigned short*)(vb + (size_t)(klo + g * 8 + 2) * QKV_LD);
                unsigned short a3 = *(const unsigned short*)(vb + (size_t)(klo + g * 8 + 3) * QKV_LD);
                unsigned short a4 = *(const unsigned short*)(vb + (size_t)(klo + g * 8 + 4) * QKV_LD);
                unsigned short a5 = *(const unsigned short*)(vb + (size_t)(klo + g * 8 + 5) * QKV_LD);
                unsigned short a6 = *(const unsigned short*)(vb + (size_t)(klo + g * 8 + 6) * QKV_LD);
                unsigned short a7 = *(const unsigned short*)(vb + (size_t)(klo + g * 8 + 7) * QKV_LD);
                u0 = (unsigned int)a0 | ((unsigned int)a1 << 16);
                u1 = (unsigned int)a2 | ((unsigned int)a3 << 16);
                u2 = (unsigned int)a4 | ((unsigned int)a5 << 16);
                u3 = (unsigned int)a6 | ((unsigned int)a7 << 16);
            }
            int cs = g ^ (h & 7);
            *(uint4*)(Vt + h * PLD + cs * 8) = make_uint4(u0, u1, u2, u3);
        }
    }

    // ---- Q fragments direct from global (A-layout: row=fr, k=quad*8+j)
    const int qrow0 = q0 + wave * 16;
    bf16x8 aq0 = *(const bf16x8*)(qkv + rowbase + (size_t)(qrow0 + fr) * QKV_LD + quad * 8);
    bf16x8 aq1 = *(const bf16x8*)(qkv + rowbase + (size_t)(qrow0 + fr) * QKV_LD + 32 + quad * 8);

    const int* mb = mask + b * SEQ;
    int mq[4];
#pragma unroll
    for (int r = 0; r < 4; r++) mq[r] = mb[qrow0 + quad * 4 + r];

    __syncthreads();

    // ---- QK^T via MFMA over key tiles
    f32x4 sc[12];
#pragma unroll
    for (int kt = 0; kt < 12; kt++) sc[kt] = (f32x4){-1e30f, -1e30f, -1e30f, -1e30f};

#pragma unroll
    for (int kt = 0; kt < 12; kt++) {
        if (kt < nt) {
            int krow = kt * 16 + fr;
            int kg = klo + krow;
            int p0 = (quad) ^ (krow & 7);
            int p1 = (4 + quad) ^ (krow & 7);
            bf16x8 bk0 = *(const bf16x8*)(Ks + krow * 64 + p0 * 8);
            bf16x8 bk1 = *(const bf16x8*)(Ks + krow * 64 + p1 * 8);
            f32x4 a = (f32x4){0.f, 0.f, 0.f, 0.f};
            a = __builtin_amdgcn_mfma_f32_16x16x32_bf16(aq0, bk0, a, 0, 0, 0);
            a = __builtin_amdgcn_mfma_f32_16x16x32_bf16(aq1, bk1, a, 0, 0, 0);
            int mk = mb[kg];
            f32x4 s;
#pragma unroll
            for (int r = 0; r < 4; r++) {
                int qg = qrow0 + quad * 4 + r;
                bool ok = (abs(qg - kg) <= WIN) && (mk != 0) && (mq[r] != 0);
                s[r] = ok ? a[r] * 0.125f : -1e30f;
            }
            sc[kt] = s;
        }
    }

    // ---- in-register softmax: reduce across fr lanes (same quad group)
    f32x4 mx = sc[0];
#pragma unroll
    for (int kt = 1; kt < 12; kt++)
#pragma unroll
        for (int r = 0; r < 4; r++) mx[r] = fmaxf(mx[r], sc[kt][r]);
#pragma unroll
    for (int off = 8; off >= 1; off >>= 1)
#pragma unroll
        for (int r = 0; r < 4; r++) mx[r] = fmaxf(mx[r], __shfl_xor(mx[r], off));

    f32x4 sum = (f32x4){0.f, 0.f, 0.f, 0.f};
#pragma unroll
    for (int kt = 0; kt < 12; kt++)
#pragma unroll
        for (int r = 0; r < 4; r++) {
            float e = __expf(sc[kt][r] - mx[r]);
            sc[kt][r] = e;
            sum[r] += e;
        }
#pragma unroll
    for (int off = 8; off >= 1; off >>= 1)
#pragma unroll
        for (int r = 0; r < 4; r++) sum[r] += __shfl_xor(sum[r], off);
    f32x4 rs;
#pragma unroll
    for (int r = 0; r < 4; r++) rs[r] = 1.0f / sum[r];

    // ---- write P (bf16, A-layout-friendly, swizzled) into Ks space
    __syncthreads();   // all waves done reading Ks
#pragma unroll
    for (int kt = 0; kt < 12; kt++) {
        if (kt < nt) {
#pragma unroll
            for (int r = 0; r < 4; r++) {
                int prow = wave * 16 + quad * 4 + r;
                int c = kt * 2 + (fr >> 3);
                int cs = c ^ (prow & 7);
                Pb[prow * PLD + cs * 8 + (fr & 7)] = __float2bfloat16(sc[kt][r] * rs[r]);
            }
        }
    }
    __syncthreads();

    // ---- PV via MFMA: O[16q][64h] per wave
    f32x4 o[4];
#pragma unroll
    for (int ht = 0; ht < 4; ht++) o[ht] = (f32x4){0.f, 0.f, 0.f, 0.f};

#pragma unroll
    for (int kc = 0; kc < 6; kc++) {
        if (kc < nkc) {
            int cs = (kc * 4 + quad) ^ (fr & 7);
            bf16x8 ap = *(const bf16x8*)(Pb + (wave * 16 + fr) * PLD + cs * 8);
#pragma unroll
            for (int ht = 0; ht < 4; ht++) {
                bf16x8 bv = *(const bf16x8*)(Vt + (ht * 16 + fr) * PLD + cs * 8);
                o[ht] = __builtin_amdgcn_mfma_f32_16x16x32_bf16(ap, bv, o[ht], 0, 0, 0);
            }
        }
    }

    // ---- store O (bf16) to attn [B*T, 768]
    __hip_bfloat16* ob = attn + (size_t)(b * SEQ + qrow0) * DMODEL + head * HDIM;
#pragma unroll
    for (int r = 0; r < 4; r++)
#pragma unroll
        for (int ht = 0; ht < 4; ht++)
            ob[(size_t)(quad * 4 + r) * DMODEL + ht * 16 + fr] = __float2bfloat16(o[ht][r]);
}

// ---------------------------------------------------------------------------
extern "C" void kernel_launch(void* const* d_in, const int* in_sizes, int n_in,
                              void* d_out, int out_size, void* d_ws, size_t ws_size,
                              hipStream_t stream) {
    const float* hidden = (const float*)d_in[0];
    const int*   mask   = (const int*)d_in[1];
    const float* Wqkv   = (const float*)d_in[2];
    const float* Wo     = (const float*)d_in[3];
    float* out = (float*)d_out;

    char* w = (char*)d_ws;
    __hip_bfloat16* qkv_bf  = (__hip_bfloat16*)(w);              // 37,748,736
    __hip_bfloat16* hid_bf  = (__hip_bfloat16*)(w + 37748736);   // 12,582,912
    __hip_bfloat16* wqkv_bf = (__hip_bfloat16*)(w + 50331648);   //  3,538,944
    __hip_bfloat16* wo_bf   = (__hip_bfloat16*)(w + 53870592);   //  1,179,648
    __hip_bfloat16* attn_bf = (__hip_bfloat16*)(w + 55050240);   // 12,582,912
    float2*         tab     = (float2*)(w + 67633152);           //    524,288

    // 0) fused setup: casts + rope table (one launch)
    setup_kernel<<<SETUP_TOTAL / 256, 256, 0, stream>>>(hidden, Wqkv, Wo,
                                                        hid_bf, wqkv_bf, wo_bf, tab);

    // 1) QKV projection + fused RoPE (BK=32 counted-vmcnt ring, 32 KB LDS
    //    -> 4-5 blocks/CU; 1152-block XCD-swizzled grid)
    gemm_k32<__hip_bfloat16, 2, true><<<18 * 64, 256, 0, stream>>>(hid_bf, wqkv_bf, qkv_bf,
                                                                   DMODEL, DMODEL, QKV_LD, tab);

    // 2) sliding-window attention (XCD-swizzled 1D grid)
    attn_kernel<<<(SEQ / 64) * NHEADS * BATCH, 256, 0, stream>>>(qkv_bf, mask, attn_bf);

    // 3) output projection (BK=32 ring, 24 KB LDS, 768 blocks = 3/CU)
    gemm_k32<float, 1, false><<<12 * 64, 256, 0, stream>>>(attn_bf, wo_bf, out,
                                                           DMODEL, DMODEL, DMODEL, nullptr);
}

// Round 7
// 170.844 us; speedup vs baseline: 1.0823x; 1.0823x over previous
//
#include <hip/hip_runtime.h>
#include <hip/hip_bf16.h>
#include <math.h>

// Problem constants (ModernBERT attention)
#define BATCH 4
#define SEQ   2048
#define DMODEL 768
#define NHEADS 12
#define HDIM  64
#define WIN   64          // window each side
#define QKV_LD 2304       // 3*DMODEL

typedef __attribute__((ext_vector_type(8))) short bf16x8;  // 8 bf16 = 4 VGPRs
typedef __attribute__((ext_vector_type(4))) float f32x4;

typedef __attribute__((address_space(1))) const unsigned int guint;
typedef __attribute__((address_space(3))) unsigned int luint;

__device__ inline void gl_lds16(const __hip_bfloat16* g, __hip_bfloat16* l) {
    __builtin_amdgcn_global_load_lds((guint*)g, (luint*)l, 16, 0, 0);
}

__device__ inline void to_out(float* p, float v) { *p = v; }
__device__ inline void to_out(__hip_bfloat16* p, float v) { *p = __float2bfloat16(v); }

// ---------------------------------------------------------------------------
// fused setup: cast hidden/Wqkv/Wo to bf16 + build rope cos/sin table.
// ---------------------------------------------------------------------------
#define N4_HID  (BATCH * SEQ * DMODEL / 4)     // 1,572,864
#define N4_WQKV (QKV_LD * DMODEL / 4)          //   442,368
#define N4_WO   (DMODEL * DMODEL / 4)          //   147,456
#define N_ROPE  (SEQ * 32)                     //    65,536
#define SETUP_TOTAL (N4_HID + N4_WQKV + N4_WO + N_ROPE)

__device__ inline void cast4(const float* in, __hip_bfloat16* out, int i) {
    float4 v = ((const float4*)in)[i];
    union { ushort4 u; __hip_bfloat16 h[4]; } o;
    o.h[0] = __float2bfloat16(v.x); o.h[1] = __float2bfloat16(v.y);
    o.h[2] = __float2bfloat16(v.z); o.h[3] = __float2bfloat16(v.w);
    ((ushort4*)out)[i] = o.u;
}

__global__ __launch_bounds__(256) void setup_kernel(const float* __restrict__ hidden,
                                                    const float* __restrict__ Wqkv,
                                                    const float* __restrict__ Wo,
                                                    __hip_bfloat16* __restrict__ hid_bf,
                                                    __hip_bfloat16* __restrict__ wqkv_bf,
                                                    __hip_bfloat16* __restrict__ wo_bf,
                                                    float2* __restrict__ tab) {
    int id = blockIdx.x * 256 + threadIdx.x;
    if (id < N4_HID) {
        cast4(hidden, hid_bf, id);
    } else if (id < N4_HID + N4_WQKV) {
        cast4(Wqkv, wqkv_bf, id - N4_HID);
    } else if (id < N4_HID + N4_WQKV + N4_WO) {
        cast4(Wo, wo_bf, id - N4_HID - N4_WQKV);
    } else if (id < SETUP_TOTAL) {
        int idx = id - (N4_HID + N4_WQKV + N4_WO);
        int t = idx >> 5, j = idx & 31;
        const float L2T_OVER_32 = 13.287712379549449f / 32.0f;  // log2(10000)/32
        float inv = exp2f(-(float)j * L2T_OVER_32);
        float s, c;
        sincosf((float)t * inv, &s, &c);
        tab[idx] = make_float2(c, s);
    }
}

// ---------------------------------------------------------------------------
// Counted-vmcnt ring bf16 MFMA NT GEMM (R3/R5 schedule -- best measured for
// QKV across R1-R6: 42-50us plateau; BK=32 (R6) and full-drain (R4) both
// regressed). BM=128, BN=64*NWN, BK=64, K=768 (12 K-tiles). 4 waves.
// ---------------------------------------------------------------------------
template <typename OutT, int NWN, bool ROPE>
__global__ __launch_bounds__(256) void gemm_ring(const __hip_bfloat16* __restrict__ A,
                                                 const __hip_bfloat16* __restrict__ B,
                                                 OutT* __restrict__ C,
                                                 int lda, int ldb, int ldc,
                                                 const float2* __restrict__ rope_tab) {
    constexpr int BN    = 64 * NWN;       // 128 or 64
    constexpr int NWM   = 4 / NWN;        // 2 or 4
    constexpr int WM    = 128 / NWM;      // 64 or 32
    constexpr int MI    = WM / 16;        // 4 or 2
    constexpr int ASLOT = 128 * 64;       // elements per A ring slot
    constexpr int BSLOT = BN * 64;        // elements per B ring slot

    __shared__ __align__(16) __hip_bfloat16 As[2 * ASLOT];
    __shared__ __align__(16) __hip_bfloat16 Bs[2 * BSLOT];

    const int tid  = threadIdx.x;
    const int lane = tid & 63;
    const int wave = tid >> 6;     // 0..3
    const int wm   = wave / NWN;
    const int wn   = wave % NWN;
    const int fr   = lane & 15;
    const int quad = lane >> 4;

    // XCD-aware swizzle (gridM = 64 m-tiles, 8 per XCD)
    const int bid = blockIdx.x;
    const int x   = bid & 7;
    const int j   = bid >> 3;
    const int m0  = (x * 8 + (j & 7)) * 128;
    const int n0  = (j >> 3) * BN;

    f32x4 acc[MI][4];
#pragma unroll
    for (int i = 0; i < MI; i++)
#pragma unroll
        for (int jj = 0; jj < 4; jj++) acc[i][jj] = (f32x4){0.f, 0.f, 0.f, 0.f};

    auto stage = [&](int t) {
        const int s  = t & 1;
        const int k0 = t * 64;
#pragma unroll
        for (int c = 0; c < 4; ++c) {
            int tc  = (wave * 4 + c) * 64 + lane;   // 0..1023
            int row = tc >> 3, ch = tc & 7;
            int gcol = (ch ^ (row & 7)) * 8;
            gl_lds16(A + (size_t)(m0 + row) * lda + k0 + gcol, As + s * ASLOT + tc * 8);
        }
#pragma unroll
        for (int c = 0; c < 2 * NWN; ++c) {
            int tc  = (wave * 2 * NWN + c) * 64 + lane;  // 0..(BN*8-1)
            int row = tc >> 3, ch = tc & 7;
            int gcol = (ch ^ (row & 7)) * 8;
            gl_lds16(B + (size_t)(n0 + row) * ldb + k0 + gcol, Bs + s * BSLOT + tc * 8);
        }
    };

    stage(0); stage(1);

#pragma unroll
    for (int t = 0; t < 12; ++t) {
        if (t < 11) {
            if constexpr (NWN == 2) asm volatile("s_waitcnt vmcnt(8)" ::: "memory");
            else                    asm volatile("s_waitcnt vmcnt(6)" ::: "memory");
        } else {
            asm volatile("s_waitcnt vmcnt(0)" ::: "memory");
        }
        __builtin_amdgcn_s_barrier();          // raw: no implicit drain
        __builtin_amdgcn_sched_barrier(0);     // pin: no reads hoisted above

        const __hip_bfloat16* as = As + (t & 1) * ASLOT;
        const __hip_bfloat16* bs = Bs + (t & 1) * BSLOT;
#pragma unroll
        for (int ks = 0; ks < 2; ++ks) {
            bf16x8 af[MI], bfv[4];
#pragma unroll
            for (int mi = 0; mi < MI; ++mi) {
                int row = wm * WM + mi * 16 + fr;
                int pos = (ks * 4 + quad) ^ (row & 7);
                af[mi] = *(const bf16x8*)(as + row * 64 + pos * 8);
            }
#pragma unroll
            for (int ni = 0; ni < 4; ++ni) {
                int row = wn * 64 + ni * 16 + fr;
                int pos = (ks * 4 + quad) ^ (row & 7);
                bfv[ni] = *(const bf16x8*)(bs + row * 64 + pos * 8);
            }
            __builtin_amdgcn_s_setprio(1);
#pragma unroll
            for (int mi = 0; mi < MI; ++mi)
#pragma unroll
                for (int ni = 0; ni < 4; ++ni)
                    acc[mi][ni] = __builtin_amdgcn_mfma_f32_16x16x32_bf16(af[mi], bfv[ni], acc[mi][ni], 0, 0, 0);
            __builtin_amdgcn_s_setprio(0);
        }

        if (t < 10) {
            __builtin_amdgcn_s_barrier();      // all waves done reading slot t&1
            __builtin_amdgcn_sched_barrier(0);
            stage(t + 2);                      // refill the vacated slot
        }
    }

    const int b0 = n0 + wn * 64;
    if (ROPE && b0 < 2 * DMODEL) {
#pragma unroll
        for (int mi = 0; mi < MI; mi++) {
#pragma unroll
            for (int r = 0; r < 4; r++) {
                int t = (m0 + wm * WM + mi * 16 + quad * 4 + r) & (SEQ - 1);
#pragma unroll
                for (int ni = 0; ni < 2; ni++) {
                    float2 cs = rope_tab[t * 32 + ni * 16 + fr];
                    float x0 = acc[mi][ni][r], x1 = acc[mi][ni + 2][r];
                    acc[mi][ni][r]     = x0 * cs.x - x1 * cs.y;
                    acc[mi][ni + 2][r] = x0 * cs.y + x1 * cs.x;
                }
            }
        }
    }

#pragma unroll
    for (int mi = 0; mi < MI; mi++)
#pragma unroll
        for (int ni = 0; ni < 4; ni++) {
            f32x4 v = acc[mi][ni];
            int gc = b0 + ni * 16 + fr;
            size_t rbase = (size_t)(m0 + wm * WM + mi * 16 + quad * 4);
#pragma unroll
            for (int r = 0; r < 4; r++)
                to_out(&C[(rbase + r) * ldc + gc], v[r]);
        }
}

// ---------------------------------------------------------------------------
// Sliding-window attention, one block per (b, head, 64-query tile).
// R7 restructure (T14 async-stage split):
//   - K staged via global_load_lds (pre-swizzled source, lane-linear dest;
//     byte-identical LDS image to the old reg-staged path).
//   - V's 48 (or 32) scalar global loads ISSUED before the K-ready barrier,
//     held in registers; packed + written to Vt only AFTER QK^T+softmax so
//     their HBM latency hides under the MFMA/VALU phase.
//   - K-ready barrier is a counted-vmcnt raw barrier: retire K's 6 loads
//     (oldest, order pinned by sched_barrier) while V's stay in flight.
// LDS 48 KB -> 3 blocks/CU.
// ---------------------------------------------------------------------------
#define PLD  192

__global__ __launch_bounds__(256) void attn_kernel(const __hip_bfloat16* __restrict__ qkv,
                                                   const int* __restrict__ mask,
                                                   __hip_bfloat16* __restrict__ attn) {
    __shared__ __align__(16) char smem[49152];
    __hip_bfloat16* Ks = (__hip_bfloat16*)smem;            // [192][64] swizzled
    __hip_bfloat16* Pb = (__hip_bfloat16*)smem;            // [64][192] swizzled (aliases Ks)
    __hip_bfloat16* Vt = (__hip_bfloat16*)(smem + 24576);  // [64][192] swizzled

    const int tid  = threadIdx.x;
    const int lane = tid & 63;
    const int wave = tid >> 6;
    const int fr   = lane & 15;
    const int quad = lane >> 4;

    // XCD-aware swizzle: 1536 blocks = 8 XCDs x 192
    const int bid  = blockIdx.x;
    const int x    = bid & 7;
    const int j    = bid >> 3;                 // 0..191
    const int b    = x >> 1;
    const int q0   = ((x & 1) * 16 + (j & 15)) * 64;
    const int head = j >> 4;                   // 0..11

    const int klo = max(0, q0 - WIN);
    const int khi = min(SEQ, q0 + 64 + WIN);
    const int nk  = khi - klo;     // 128 or 192
    const int nt  = nk >> 4;       // 8 or 12
    const int nkc = nk >> 5;       // 4 or 6
    const int ng  = nk >> 3;       // 16 or 24 V row-groups

    const size_t rowbase = (size_t)(b * SEQ) * QKV_LD + head * HDIM;

    // ---- Q fragments + q-mask first (oldest vmem, consumed via compiler waits)
    const int qrow0 = q0 + wave * 16;
    bf16x8 aq0 = *(const bf16x8*)(qkv + rowbase + (size_t)(qrow0 + fr) * QKV_LD + quad * 8);
    bf16x8 aq1 = *(const bf16x8*)(qkv + rowbase + (size_t)(qrow0 + fr) * QKV_LD + 32 + quad * 8);
    const int* mb = mask + b * SEQ;
    int mq[4];
#pragma unroll
    for (int r = 0; r < 4; r++) mq[r] = mb[qrow0 + quad * 4 + r];

    // ---- K staging via global_load_lds: LDS chunk c holds global chunk
    //      c^(row&7) (same image as before); dest lane-linear (required).
    for (int task = tid; task < nk * 8; task += 256) {
        int row = task >> 3, c = task & 7;
        int gcol = (c ^ (row & 7)) * 8;
        gl_lds16(qkv + rowbase + (size_t)(klo + row) * QKV_LD + DMODEL + gcol,
                 Ks + task * 8);
    }
    __builtin_amdgcn_sched_barrier(0);   // pin: K loads older than V loads

    // ---- V loads issued NOW, consumed after QK^T (T14 split).
    //      group g covers rows klo+g*8..+8, this thread's column h=lane.
    unsigned short va[6][8];
    {
        const __hip_bfloat16* vb = qkv + rowbase + 2 * DMODEL + lane;
#pragma unroll
        for (int idx = 0; idx < 6; ++idx) {
            int g = wave + idx * 4;
            if (g < ng) {
#pragma unroll
                for (int e = 0; e < 8; ++e)
                    va[idx][e] = *(const unsigned short*)(vb + (size_t)(klo + g * 8 + e) * QKV_LD);
            }
        }
    }
    __builtin_amdgcn_sched_barrier(0);   // pin: nothing sinks below the wait

    // ---- K-ready barrier: retire K's 6 gl_lds (oldest); V's stay in flight.
    if (ng == 24) asm volatile("s_waitcnt vmcnt(48)" ::: "memory");
    else          asm volatile("s_waitcnt vmcnt(32)" ::: "memory");
    __builtin_amdgcn_s_barrier();
    __builtin_amdgcn_sched_barrier(0);

    // ---- QK^T via MFMA over key tiles (V latency hides under this)
    f32x4 sc[12];
#pragma unroll
    for (int kt = 0; kt < 12; kt++) sc[kt] = (f32x4){-1e30f, -1e30f, -1e30f, -1e30f};

#pragma unroll
    for (int kt = 0; kt < 12; kt++) {
        if (kt < nt) {
            int krow = kt * 16 + fr;
            int kg = klo + krow;
            int p0 = (quad) ^ (krow & 7);
            int p1 = (4 + quad) ^ (krow & 7);
            bf16x8 bk0 = *(const bf16x8*)(Ks + krow * 64 + p0 * 8);
            bf16x8 bk1 = *(const bf16x8*)(Ks + krow * 64 + p1 * 8);
            f32x4 a = (f32x4){0.f, 0.f, 0.f, 0.f};
            a = __builtin_amdgcn_mfma_f32_16x16x32_bf16(aq0, bk0, a, 0, 0, 0);
            a = __builtin_amdgcn_mfma_f32_16x16x32_bf16(aq1, bk1, a, 0, 0, 0);
            int mk = mb[kg];
            f32x4 s;
#pragma unroll
            for (int r = 0; r < 4; r++) {
                int qg = qrow0 + quad * 4 + r;
                bool ok = (abs(qg - kg) <= WIN) && (mk != 0) && (mq[r] != 0);
                s[r] = ok ? a[r] * 0.125f : -1e30f;
            }
            sc[kt] = s;
        }
    }

    // ---- in-register softmax: reduce across fr lanes (same quad group)
    f32x4 mx = sc[0];
#pragma unroll
    for (int kt = 1; kt < 12; kt++)
#pragma unroll
        for (int r = 0; r < 4; r++) mx[r] = fmaxf(mx[r], sc[kt][r]);
#pragma unroll
    for (int off = 8; off >= 1; off >>= 1)
#pragma unroll
        for (int r = 0; r < 4; r++) mx[r] = fmaxf(mx[r], __shfl_xor(mx[r], off));

    f32x4 sum = (f32x4){0.f, 0.f, 0.f, 0.f};
#pragma unroll
    for (int kt = 0; kt < 12; kt++)
#pragma unroll
        for (int r = 0; r < 4; r++) {
            float e = __expf(sc[kt][r] - mx[r]);
            sc[kt][r] = e;
            sum[r] += e;
        }
#pragma unroll
    for (int off = 8; off >= 1; off >>= 1)
#pragma unroll
        for (int r = 0; r < 4; r++) sum[r] += __shfl_xor(sum[r], off);
    f32x4 rs;
#pragma unroll
    for (int r = 0; r < 4; r++) rs[r] = 1.0f / sum[r];

    // ---- NOW pack + write V transposed (loads have had QK^T+softmax of cover)
    {
        int h = lane;
#pragma unroll
        for (int idx = 0; idx < 6; ++idx) {
            int g = wave + idx * 4;
            if (g < ng) {
                unsigned int u0 = (unsigned int)va[idx][0] | ((unsigned int)va[idx][1] << 16);
                unsigned int u1 = (unsigned int)va[idx][2] | ((unsigned int)va[idx][3] << 16);
                unsigned int u2 = (unsigned int)va[idx][4] | ((unsigned int)va[idx][5] << 16);
                unsigned int u3 = (unsigned int)va[idx][6] | ((unsigned int)va[idx][7] << 16);
                int cs = g ^ (h & 7);
                *(uint4*)(Vt + h * PLD + cs * 8) = make_uint4(u0, u1, u2, u3);
            }
        }
    }

    // ---- write P (bf16, A-layout-friendly, swizzled) into Ks space
    __syncthreads();   // all waves done reading Ks; Vt writes drained
#pragma unroll
    for (int kt = 0; kt < 12; kt++) {
        if (kt < nt) {
#pragma unroll
            for (int r = 0; r < 4; r++) {
                int prow = wave * 16 + quad * 4 + r;
                int c = kt * 2 + (fr >> 3);
                int cs = c ^ (prow & 7);
                Pb[prow * PLD + cs * 8 + (fr & 7)] = __float2bfloat16(sc[kt][r] * rs[r]);
            }
        }
    }
    __syncthreads();

    // ---- PV via MFMA: O[16q][64h] per wave
    f32x4 o[4];
#pragma unroll
    for (int ht = 0; ht < 4; ht++) o[ht] = (f32x4){0.f, 0.f, 0.f, 0.f};

#pragma unroll
    for (int kc = 0; kc < 6; kc++) {
        if (kc < nkc) {
            int cs = (kc * 4 + quad) ^ (fr & 7);
            bf16x8 ap = *(const bf16x8*)(Pb + (wave * 16 + fr) * PLD + cs * 8);
#pragma unroll
            for (int ht = 0; ht < 4; ht++) {
                bf16x8 bv = *(const bf16x8*)(Vt + (ht * 16 + fr) * PLD + cs * 8);
                o[ht] = __builtin_amdgcn_mfma_f32_16x16x32_bf16(ap, bv, o[ht], 0, 0, 0);
            }
        }
    }

    // ---- store O (bf16) to attn [B*T, 768]
    __hip_bfloat16* ob = attn + (size_t)(b * SEQ + qrow0) * DMODEL + head * HDIM;
#pragma unroll
    for (int r = 0; r < 4; r++)
#pragma unroll
        for (int ht = 0; ht < 4; ht++)
            ob[(size_t)(quad * 4 + r) * DMODEL + ht * 16 + fr] = __float2bfloat16(o[ht][r]);
}

// ---------------------------------------------------------------------------
extern "C" void kernel_launch(void* const* d_in, const int* in_sizes, int n_in,
                              void* d_out, int out_size, void* d_ws, size_t ws_size,
                              hipStream_t stream) {
    const float* hidden = (const float*)d_in[0];
    const int*   mask   = (const int*)d_in[1];
    const float* Wqkv   = (const float*)d_in[2];
    const float* Wo     = (const float*)d_in[3];
    float* out = (float*)d_out;

    char* w = (char*)d_ws;
    __hip_bfloat16* qkv_bf  = (__hip_bfloat16*)(w);              // 37,748,736
    __hip_bfloat16* hid_bf  = (__hip_bfloat16*)(w + 37748736);   // 12,582,912
    __hip_bfloat16* wqkv_bf = (__hip_bfloat16*)(w + 50331648);   //  3,538,944
    __hip_bfloat16* wo_bf   = (__hip_bfloat16*)(w + 53870592);   //  1,179,648
    __hip_bfloat16* attn_bf = (__hip_bfloat16*)(w + 55050240);   // 12,582,912
    float2*         tab     = (float2*)(w + 67633152);           //    524,288

    // 0) fused setup: casts + rope table (one launch)
    setup_kernel<<<SETUP_TOTAL / 256, 256, 0, stream>>>(hidden, Wqkv, Wo,
                                                        hid_bf, wqkv_bf, wo_bf, tab);

    // 1) QKV projection + fused RoPE (R3/R5 counted-vmcnt ring, 128x128)
    gemm_ring<__hip_bfloat16, 2, true><<<18 * 64, 256, 0, stream>>>(hid_bf, wqkv_bf, qkv_bf,
                                                                    DMODEL, DMODEL, QKV_LD, tab);

    // 2) sliding-window attention (T14 async-stage split)
    attn_kernel<<<(SEQ / 64) * NHEADS * BATCH, 256, 0, stream>>>(qkv_bf, mask, attn_bf);

    // 3) output projection (ring schedule, 128x64 tiles -> 768 blocks = 3/CU)
    gemm_ring<float, 1, false><<<12 * 64, 256, 0, stream>>>(attn_bf, wo_bf, out,
                                                            DMODEL, DMODEL, DMODEL, nullptr);
}